// Round 2
// baseline (318.735 us; speedup 1.0000x reference)
//
#include <hip/hip_runtime.h>
#include <stdint.h>

#define N_NODES 6144
#define F_IN 512
#define NHEAD 4
#define FH 64
#define HF 256   // NHEAD*FH
#define NCLS 40
#define CAP 192
#define LRELU_ALPHA 0.2f

typedef __bf16 bf16x8 __attribute__((ext_vector_type(8)));
typedef float floatx4 __attribute__((ext_vector_type(4)));

__device__ __forceinline__ uint16_t f2b(float f){
    union { float f; uint32_t i; } x; x.f = f;
    uint32_t r = x.i + 0x7FFFu + ((x.i >> 16) & 1u);
    return (uint16_t)(r >> 16);
}

// ---------------- K0a: convert x fp32 -> bf16 ----------------
__global__ void k_cvt_x(const float* __restrict__ x, uint16_t* __restrict__ xb){
    int idx = (blockIdx.x * 256 + threadIdx.x) * 4;   // total 3,145,728 elems
    float4 v = *reinterpret_cast<const float4*>(x + idx);
    ushort4 o;
    o.x = f2b(v.x); o.y = f2b(v.y); o.z = f2b(v.z); o.w = f2b(v.w);
    *reinterpret_cast<ushort4*>(xb + idx) = o;
}

// ---------------- K0b: transpose+convert W [H,F,Fh] fp32 -> Wt [HF, F] bf16 ----------------
__global__ void k_transpose_w(const float* __restrict__ W, uint16_t* __restrict__ Wt){
    int idx = blockIdx.x * 256 + threadIdx.x;      // 0 .. 131071
    int c = idx >> 9, k = idx & 511;               // c = output row (h*64+f), k
    Wt[idx] = f2b(W[((c >> 6) << 15) + k * 64 + (c & 63)]);
}

// ---------------- K1: dense fp32 adj row scan -> CSR-ish neighbor lists ----------------
__global__ void k_build_csr(const float* __restrict__ adj, int* __restrict__ cnt,
                            int* __restrict__ idxbuf){
    __shared__ int scnt;
    int i = blockIdx.x, t = threadIdx.x;
    if (t == 0) scnt = 0;
    __syncthreads();
    const float4* row = reinterpret_cast<const float4*>(adj + (size_t)i * N_NODES);
    int* out = idxbuf + (size_t)i * CAP;
    for (int q = t; q < N_NODES / 4; q += 256){
        float4 v = row[q];
        int j0 = q * 4;
        if (v.x != 0.f){ int p = atomicAdd(&scnt, 1); if (p < CAP) out[p] = j0;     }
        if (v.y != 0.f){ int p = atomicAdd(&scnt, 1); if (p < CAP) out[p] = j0 + 1; }
        if (v.z != 0.f){ int p = atomicAdd(&scnt, 1); if (p < CAP) out[p] = j0 + 2; }
        if (v.w != 0.f){ int p = atomicAdd(&scnt, 1); if (p < CAP) out[p] = j0 + 3; }
    }
    __syncthreads();
    if (t == 0) cnt[i] = scnt < CAP ? scnt : CAP;
}

// ---------------- K2: Wh1 = x @ Wcat  (bf16 MFMA, fp32 out) ----------------
// grid (192, 8), block 256. Block tile 32 rows x 32 cols; wave = one 16x16 tile.
__global__ void k_gemm1(const uint16_t* __restrict__ xb, const uint16_t* __restrict__ Wt,
                        float* __restrict__ Wh1){
    int w = threadIdx.x >> 6, l = threadIdx.x & 63;
    int r0 = blockIdx.x * 32 + (w & 1) * 16;
    int c0 = blockIdx.y * 32 + (w >> 1) * 16;
    int m = l & 15, q = l >> 4;
    const uint16_t* ap = xb + (size_t)(r0 + m) * F_IN + q * 8;
    const uint16_t* bp = Wt + (size_t)(c0 + m) * F_IN + q * 8;
    floatx4 acc = {0.f, 0.f, 0.f, 0.f};
    for (int k0 = 0; k0 < F_IN; k0 += 32){
        bf16x8 a = *reinterpret_cast<const bf16x8*>(ap + k0);
        bf16x8 b = *reinterpret_cast<const bf16x8*>(bp + k0);
        acc = __builtin_amdgcn_mfma_f32_16x16x32_bf16(a, b, acc, 0, 0, 0);
    }
    int col = c0 + m;
    int rowb = r0 + q * 4;
    #pragma unroll
    for (int r = 0; r < 4; r++)
        Wh1[(size_t)(rowb + r) * HF + col] = acc[r];
}

// ---------------- K3: f1[h,n], f2[h,n] = Wh1[n, h*64:...] . a1/a2 ----------------
__global__ void k_f12(const float* __restrict__ Wh1, const float* __restrict__ a1,
                      const float* __restrict__ a2, float* __restrict__ f1,
                      float* __restrict__ f2){
    int n = blockIdx.x;
    int h = threadIdx.x >> 6, l = threadIdx.x & 63;
    float w = Wh1[(size_t)n * HF + h * FH + l];
    float s1 = w * a1[h * FH + l];
    float s2 = w * a2[h * FH + l];
    for (int off = 32; off; off >>= 1){
        s1 += __shfl_xor(s1, off);
        s2 += __shfl_xor(s2, off);
    }
    if (l == 0){ f1[h * N_NODES + n] = s1; f2[h * N_NODES + n] = s2; }
}

// ---------------- K4: layer-1 sparse attention + ELU -> hcat [N, 256] ----------------
// grid (6144, 4), block 64 (one wave per (row, head))
__global__ void k_attn1(const int* __restrict__ cnt, const int* __restrict__ idxbuf,
                        const float* __restrict__ Wh1, const float* __restrict__ f1,
                        const float* __restrict__ f2, float* __restrict__ hcat){
    int i = blockIdx.x, h = blockIdx.y, l = threadIdx.x;
    int c = cnt[i];
    __shared__ int   sidx[CAP];
    __shared__ float sp[CAP];
    const int* src = idxbuf + (size_t)i * CAP;
    for (int e = l; e < c; e += 64) sidx[e] = src[e];
    __syncthreads();
    float f1i = f1[h * N_NODES + i];
    float mx = -1e30f;
    for (int e = l; e < c; e += 64){
        float s = f1i + f2[h * N_NODES + sidx[e]];
        s = s > 0.f ? s : LRELU_ALPHA * s;
        sp[e] = s;
        mx = fmaxf(mx, s);
    }
    for (int off = 32; off; off >>= 1) mx = fmaxf(mx, __shfl_xor(mx, off));
    __syncthreads();
    float ssum = 0.f;
    for (int e = l; e < c; e += 64){
        float p = __expf(sp[e] - mx);
        sp[e] = p;
        ssum += p;
    }
    for (int off = 32; off; off >>= 1) ssum += __shfl_xor(ssum, off);
    float inv = 1.f / ssum;
    __syncthreads();
    float acc = 0.f;
    const float* whb = Wh1 + h * FH + l;
    for (int e = 0; e < c; e++)
        acc += sp[e] * inv * whb[(size_t)sidx[e] * HF];
    float v = acc > 0.f ? acc : __expf(acc) - 1.f;   // ELU
    hcat[(size_t)i * HF + h * FH + l] = v;
}

// ---------------- K5: Wh2 = hcat @ Wo  (+ fused f1o/f2o) ----------------
// grid 1536, block 256: wave w handles row n = blk*4+w; lane = class (40 used)
__global__ void k_gemm2(const float* __restrict__ hcat, const float* __restrict__ Wo,
                        const float* __restrict__ ao1, const float* __restrict__ ao2,
                        float* __restrict__ Wh2, float* __restrict__ f1o,
                        float* __restrict__ f2o){
    int w = threadIdx.x >> 6, l = threadIdx.x & 63;
    int n = blockIdx.x * 4 + w;
    const float* hr = hcat + (size_t)n * HF;
    float acc = 0.f;
    if (l < NCLS){
        for (int k = 0; k < HF; k++)
            acc += hr[k] * Wo[k * NCLS + l];
    }
    float t1 = l < NCLS ? acc * ao1[l] : 0.f;
    float t2 = l < NCLS ? acc * ao2[l] : 0.f;
    for (int off = 32; off; off >>= 1){
        t1 += __shfl_xor(t1, off);
        t2 += __shfl_xor(t2, off);
    }
    if (l < NCLS) Wh2[(size_t)n * NCLS + l] = acc;
    if (l == 0){ f1o[n] = t1; f2o[n] = t2; }
}

// ---------------- K6: layer-2 attention + ELU + log_softmax -> out fp32 ----------------
// grid 6144, block 64
__global__ void k_attn2(const int* __restrict__ cnt, const int* __restrict__ idxbuf,
                        const float* __restrict__ Wh2, const float* __restrict__ f1o,
                        const float* __restrict__ f2o, float* __restrict__ out){
    int i = blockIdx.x, l = threadIdx.x;
    int c = cnt[i];
    __shared__ int   sidx[CAP];
    __shared__ float sp[CAP];
    const int* src = idxbuf + (size_t)i * CAP;
    for (int e = l; e < c; e += 64) sidx[e] = src[e];
    __syncthreads();
    float f1i = f1o[i];
    float mx = -1e30f;
    for (int e = l; e < c; e += 64){
        float s = f1i + f2o[sidx[e]];
        s = s > 0.f ? s : LRELU_ALPHA * s;
        sp[e] = s;
        mx = fmaxf(mx, s);
    }
    for (int off = 32; off; off >>= 1) mx = fmaxf(mx, __shfl_xor(mx, off));
    __syncthreads();
    float ssum = 0.f;
    for (int e = l; e < c; e += 64){
        float p = __expf(sp[e] - mx);
        sp[e] = p;
        ssum += p;
    }
    for (int off = 32; off; off >>= 1) ssum += __shfl_xor(ssum, off);
    float inv = 1.f / ssum;
    __syncthreads();
    float acc = 0.f;
    if (l < NCLS){
        for (int e = 0; e < c; e++)
            acc += sp[e] * inv * Wh2[(size_t)sidx[e] * NCLS + l];
    }
    float o = (l < NCLS) ? (acc > 0.f ? acc : __expf(acc) - 1.f) : -1e30f;
    float m2 = o;
    for (int off = 32; off; off >>= 1) m2 = fmaxf(m2, __shfl_xor(m2, off));
    float ex = (l < NCLS) ? __expf(o - m2) : 0.f;
    for (int off = 32; off; off >>= 1) ex += __shfl_xor(ex, off);
    float res = o - m2 - logf(ex);
    if (l < NCLS) out[(size_t)i * NCLS + l] = res;
}

extern "C" void kernel_launch(void* const* d_in, const int* in_sizes, int n_in,
                              void* d_out, int out_size, void* d_ws, size_t ws_size,
                              hipStream_t stream) {
    const float* x   = (const float*)d_in[0];
    const float* adj = (const float*)d_in[1];
    const float* W   = (const float*)d_in[2];
    const float* a1  = (const float*)d_in[3];
    const float* a2  = (const float*)d_in[4];
    const float* Wo  = (const float*)d_in[5];
    const float* ao1 = (const float*)d_in[6];
    const float* ao2 = (const float*)d_in[7];
    float* out = (float*)d_out;

    char* ws = (char*)d_ws;
    int*      nbr_cnt = (int*)     (ws + 0);          //     24,576 B
    int*      nbr_idx = (int*)     (ws + 24576);      //  4,718,592 B
    uint16_t* Wt      = (uint16_t*)(ws + 4743168);    //    262,144 B
    uint16_t* xb      = (uint16_t*)(ws + 5005312);    //  6,291,456 B
    float*    Wh1     = (float*)   (ws + 11296768);   //  6,291,456 B
    float*    f1      = (float*)   (ws + 17588224);   //     98,304 B
    float*    f2      = (float*)   (ws + 17686528);   //     98,304 B
    float*    hcat    = (float*)   (ws + 17784832);   //  6,291,456 B
    float*    Wh2     = (float*)   (ws + 24076288);   //    983,040 B
    float*    f1o     = (float*)   (ws + 25059328);   //     24,576 B
    float*    f2o     = (float*)   (ws + 25083904);   //     24,576 B -> total ~25.1 MB

    hipLaunchKernelGGL(k_cvt_x,       dim3(3072),       dim3(256), 0, stream, x, xb);
    hipLaunchKernelGGL(k_transpose_w, dim3(512),        dim3(256), 0, stream, W, Wt);
    hipLaunchKernelGGL(k_build_csr,   dim3(6144),       dim3(256), 0, stream, adj, nbr_cnt, nbr_idx);
    hipLaunchKernelGGL(k_gemm1,       dim3(192, 8),     dim3(256), 0, stream, xb, Wt, Wh1);
    hipLaunchKernelGGL(k_f12,         dim3(6144),       dim3(256), 0, stream, Wh1, a1, a2, f1, f2);
    hipLaunchKernelGGL(k_attn1,       dim3(6144, 4),    dim3(64),  0, stream, nbr_cnt, nbr_idx, Wh1, f1, f2, hcat);
    hipLaunchKernelGGL(k_gemm2,       dim3(1536),       dim3(256), 0, stream, hcat, Wo, ao1, ao2, Wh2, f1o, f2o);
    hipLaunchKernelGGL(k_attn2,       dim3(6144),       dim3(64),  0, stream, nbr_cnt, nbr_idx, Wh2, f1o, f2o, out);
}